// Round 5
// baseline (2192.116 us; speedup 1.0000x reference)
//
#include <hip/hip_runtime.h>
#include <math.h>

#define NH 16
#define SEQ 2048
#define DIM 128
#define NMEM 4096
#define TOPK 16
#define TQ 64                  // q-rows per WG
#define KC 256                 // keys per chunk
#define NCHUNK (NMEM / KC)     // 16
#define BD 16                  // depth slice (floats)
#define NSLICE (DIM / BD)      // 8
#define RST 20                 // Qs/Ks slice row stride (words), b128-aligned
#define SCST 36                // Sc row stride (words)
#define NTHR 256

// ---- pre-pass: inverse norms only. Partial-sum splits bitwise-match R3:
// K rows: 8 threads/row (4 f4 chain + 3 shuffle-adds); Q rows: 4 threads/row.
__global__ __launch_bounds__(256, 4)
void prenorm_kernel(const float* __restrict__ query,
                    const float* __restrict__ kmem,
                    float* __restrict__ kinvg,
                    float* __restrict__ qinvg)
{
    const int tid = threadIdx.x;
    const int bid = blockIdx.x;
    const int KB = (NH * NMEM) / 32;   // 2048 blocks for K (32 rows each)
    if (bid < KB) {
        const int row = bid * 32 + (tid >> 3);
        const int part = tid & 7;
        const float* p = kmem + (size_t)row * DIM + part * 16;
        float ss = 0.f;
#pragma unroll
        for (int j = 0; j < 4; ++j) {
            float4 v = *(const float4*)(p + j * 4);
            ss = fmaf(v.x, v.x, ss); ss = fmaf(v.y, v.y, ss);
            ss = fmaf(v.z, v.z, ss); ss = fmaf(v.w, v.w, ss);
        }
        ss += __shfl_xor(ss, 1);
        ss += __shfl_xor(ss, 2);
        ss += __shfl_xor(ss, 4);
        if (part == 0) kinvg[row] = 1.0f / fmaxf(sqrtf(ss), 1e-6f);
    } else {
        const int row = (bid - KB) * 64 + (tid >> 2);
        const int part = tid & 3;
        const float* p = query + (size_t)row * DIM + part * 32;
        float ss = 0.f;
#pragma unroll
        for (int j = 0; j < 8; ++j) {
            float4 v = *(const float4*)(p + j * 4);
            ss = fmaf(v.x, v.x, ss); ss = fmaf(v.y, v.y, ss);
            ss = fmaf(v.z, v.z, ss); ss = fmaf(v.w, v.w, ss);
        }
        ss += __shfl_xor(ss, 1);
        ss += __shfl_xor(ss, 2);
        if (part == 0) qinvg[row] = 1.0f / fmaxf(sqrtf(ss), 1e-6f);
    }
}

// ---------------- main fused kernel ----------------
__global__ __launch_bounds__(NTHR, 2)
void praxis_main(const float* __restrict__ query,
                 const float* __restrict__ outputs,
                 const float* __restrict__ gate,
                 const float* __restrict__ kmem,
                 const float* __restrict__ vmem,
                 const float* __restrict__ kinvg,
                 const float* __restrict__ qinvg,
                 float* __restrict__ out)
{
    __shared__ union SM {
        struct {
            float Qs[2][TQ * RST];     // 10 KB
            float Ks[2][KC * RST];     // 40 KB
            float Sc[2][TQ * SCST];    // 18 KB
        } a;                            // 68 KB
        struct {
            float fs[TQ][64]; int fi[TQ][64];
            float tks[TQ][TOPK]; int tki[TQ][TOPK];
        } b;                            // 40 KB
    } sm;

    const int tid = threadIdx.x;
    const int h  = blockIdx.x >> 5;        // 32 q-tiles per head
    const int q0 = (blockIdx.x & 31) * TQ;

    const float* Qg = query + ((size_t)h * SEQ + q0) * DIM;
    const float* Kg = kmem + (size_t)h * NMEM * DIM;
    const float* Vg = vmem + (size_t)h * NMEM * DIM;

    // thread roles
    const int qg = tid >> 5;   // 0..7   GEMM q-group (rows qg+8i)
    const int kg = tid & 31;   // 0..31  GEMM k-group (cols kg+32j)
    const int row = tid >> 2;  // 0..63  stage/filter/epilogue q-row
    const int part = tid & 3;  // 0..3

    const float qinv_r = qinvg[h * SEQ + q0 + row];   // for staged Q row

    // per-thread running top-16 (sorted ascending, ls[0] = threshold)
    float ls[TOPK]; int li[TOPK];
#pragma unroll
    for (int t = 0; t < TOPK; ++t) { ls[t] = -1e30f; li[t] = 0; }

    // prefetch slice t=0 (chunk 0): K key=tid 16 floats, Q row f4
    float4 kreg[4]; float4 qreg;
    {
        const float* kp = Kg + (size_t)tid * DIM;
#pragma unroll
        for (int j = 0; j < 4; ++j) kreg[j] = *(const float4*)(kp + j * 4);
        qreg = *(const float4*)(Qg + (size_t)row * DIM + part * 4);
    }
    float kinv_next = kinvg[h * NMEM + tid];   // chunk 0, key tid

#pragma unroll 1
    for (int c = 0; c < NCHUNK; ++c) {
        const float kinv_cur = kinv_next;
        if (c + 1 < NCHUNK) kinv_next = kinvg[h * NMEM + (c + 1) * KC + tid];

        float acc[8][8];
#pragma unroll
        for (int i = 0; i < 8; ++i)
#pragma unroll
            for (int j = 0; j < 8; ++j) acc[i][j] = 0.f;

#pragma unroll 1
        for (int s = 0; s < NSLICE; ++s) {
            const int buf = s & 1;
            // stage prefetched regs -> LDS, normalized (bitwise = R3's values)
            {
                float* kd = &sm.a.Ks[buf][tid * RST];
#pragma unroll
                for (int j = 0; j < 4; ++j) {
                    float4 v = kreg[j];
                    v.x *= kinv_cur; v.y *= kinv_cur; v.z *= kinv_cur; v.w *= kinv_cur;
                    *(float4*)(kd + j * 4) = v;
                }
                float4 q = qreg;
                q.x *= qinv_r; q.y *= qinv_r; q.z *= qinv_r; q.w *= qinv_r;
                *(float4*)(&sm.a.Qs[buf][row * RST + part * 4]) = q;
            }
            __syncthreads();
            // prefetch next slice
            {
                int t = c * NSLICE + s + 1;
                if (t < NCHUNK * NSLICE) {
                    int nc = t >> 3, d0 = (t & 7) * BD;
                    const float* kp = Kg + (size_t)(nc * KC + tid) * DIM + d0;
#pragma unroll
                    for (int j = 0; j < 4; ++j) kreg[j] = *(const float4*)(kp + j * 4);
                    qreg = *(const float4*)(Qg + (size_t)row * DIM + d0 + part * 4);
                }
            }
            // compute: 4 depth-quads, 8q x 8k per thread, sequential d order
#pragma unroll
            for (int d4 = 0; d4 < 4; ++d4) {
                float4 kb[8];
#pragma unroll
                for (int j = 0; j < 8; ++j)
                    kb[j] = *(const float4*)(&sm.a.Ks[buf][(kg + 32 * j) * RST + d4 * 4]);
#pragma unroll
                for (int i = 0; i < 8; ++i) {
                    float4 qa = *(const float4*)(&sm.a.Qs[buf][(qg + 8 * i) * RST + d4 * 4]);
#pragma unroll
                    for (int j = 0; j < 8; ++j) {
                        acc[i][j] = fmaf(qa.x, kb[j].x, acc[i][j]);
                        acc[i][j] = fmaf(qa.y, kb[j].y, acc[i][j]);
                        acc[i][j] = fmaf(qa.z, kb[j].z, acc[i][j]);
                        acc[i][j] = fmaf(qa.w, kb[j].w, acc[i][j]);
                    }
                }
            }
        }

        // ---- dump + filter, 8 rounds of 32 keys, double-buffered Sc halves ----
#pragma unroll 1
        for (int r = 0; r < 8; ++r) {
            const int half = r & 1;
            {
#pragma unroll
                for (int i = 0; i < 8; ++i)
                    sm.a.Sc[half][(qg + 8 * i) * SCST + kg] = acc[i][r];
            }
            __syncthreads();
            {
                float4 s0 = *(const float4*)(&sm.a.Sc[half][row * SCST + part * 8]);
                float4 s1 = *(const float4*)(&sm.a.Sc[half][row * SCST + part * 8 + 4]);
                int b0 = c * KC + r * 32 + part * 8;
                float mnv = ls[0];
                float4 grp[2] = { s0, s1 };
#pragma unroll
                for (int g = 0; g < 2; ++g) {
                    float4 v = grp[g];
                    int bg = b0 + g * 4;
                    float m01 = fmaxf(v.x, v.y); int i01 = (v.x >= v.y) ? 0 : 1;
                    float m23 = fmaxf(v.z, v.w); int i23 = (v.z >= v.w) ? 2 : 3;
                    float m   = fmaxf(m01, m23); int im  = (m01 >= m23) ? i01 : i23;
                    while (__ballot(m > mnv)) {
                        if (m > mnv) {
                            float s = m; int id = bg + im;
                            bool bp = true;
#pragma unroll
                            for (int t = 0; t < TOPK - 1; ++t) {
                                bool bt = s > ls[t + 1];
                                float nv = bt ? ls[t + 1] : (bp ? s : ls[t]);
                                int   ni = bt ? li[t + 1] : (bp ? id : li[t]);
                                ls[t] = nv; li[t] = ni; bp = bt;
                            }
                            ls[TOPK - 1] = bp ? s : ls[TOPK - 1];
                            li[TOPK - 1] = bp ? id : li[TOPK - 1];
                            mnv = ls[0];
                            v.x = (im == 0) ? -3e38f : v.x;
                            v.y = (im == 1) ? -3e38f : v.y;
                            v.z = (im == 2) ? -3e38f : v.z;
                            v.w = (im == 3) ? -3e38f : v.w;
                            m01 = fmaxf(v.x, v.y); i01 = (v.x >= v.y) ? 0 : 1;
                            m23 = fmaxf(v.z, v.w); i23 = (v.z >= v.w) ? 2 : 3;
                            m   = fmaxf(m01, m23); im  = (m01 >= m23) ? i01 : i23;
                        }
                    }
                }
            }
        }
    }

    __syncthreads();  // repurpose LDS as phase-b
    {
#pragma unroll
        for (int t = 0; t < TOPK; ++t) {
            sm.b.fs[row][part * TOPK + t] = ls[t];
            sm.b.fi[row][part * TOPK + t] = li[t];
        }
    }
    __syncthreads();
    // final selection: one wave per 16 rows; 16 rounds of wave-max over 64 cands
    {
        int wv = tid >> 6, lane = tid & 63;
        for (int rr = 0; rr < 16; ++rr) {
            int rw = wv * 16 + rr;
            float s = sm.b.fs[rw][lane];
            int  id = sm.b.fi[rw][lane];
#pragma unroll 1
            for (int it = 0; it < TOPK; ++it) {
                float m = s;
#pragma unroll
                for (int off = 32; off >= 1; off >>= 1)
                    m = fmaxf(m, __shfl_xor(m, off));
                unsigned long long bal = __ballot(s == m);
                int who = (int)__ffsll(bal) - 1;
                int selid = __shfl(id, who);
                if (lane == 0) { sm.b.tks[rw][it] = m; sm.b.tki[rw][it] = selid; }
                if (lane == who) s = -3e38f;
            }
        }
    }
    __syncthreads();
    // ---- epilogue: gather V, weighted sum (descending order), gate blend ----
    {
        float4 acc[8];
#pragma unroll
        for (int j = 0; j < 8; ++j) acc[j] = make_float4(0.f, 0.f, 0.f, 0.f);
#pragma unroll 1
        for (int t = 0; t < TOPK; ++t) {
            float s = sm.b.tks[row][t];
            int idx = sm.b.tki[row][t];
            const float* vp = Vg + (size_t)idx * DIM + part * 32;
#pragma unroll
            for (int j = 0; j < 8; ++j) {
                float4 v = *(const float4*)(vp + j * 4);
                acc[j].x = fmaf(s, v.x, acc[j].x);
                acc[j].y = fmaf(s, v.y, acc[j].y);
                acc[j].z = fmaf(s, v.z, acc[j].z);
                acc[j].w = fmaf(s, v.w, acc[j].w);
            }
        }
        float g = 1.0f / (1.0f + expf(-gate[h]));
        float og = 1.0f - g;
        size_t ob = ((size_t)h * SEQ + q0 + row) * DIM + part * 32;
#pragma unroll
        for (int j = 0; j < 8; ++j) {
            float4 o = *(const float4*)(outputs + ob + j * 4);
            float4 r;
            r.x = g * acc[j].x + og * o.x;
            r.y = g * acc[j].y + og * o.y;
            r.z = g * acc[j].z + og * o.z;
            r.w = g * acc[j].w + og * o.w;
            *(float4*)(out + ob + j * 4) = r;
        }
    }
}

extern "C" void kernel_launch(void* const* d_in, const int* in_sizes, int n_in,
                              void* d_out, int out_size, void* d_ws, size_t ws_size,
                              hipStream_t stream) {
    (void)in_sizes; (void)n_in; (void)out_size; (void)ws_size;
    const float* query   = (const float*)d_in[1];
    const float* outputs = (const float*)d_in[4];
    const float* gate    = (const float*)d_in[5];
    const float* kmem    = (const float*)d_in[6];
    const float* vmem    = (const float*)d_in[7];
    float* out = (float*)d_out;
    float* kinvg = (float*)d_ws;                 // 16*4096 floats
    float* qinvg = kinvg + NH * NMEM;            // 16*2048 floats (total 384 KB)

    prenorm_kernel<<<dim3((NH * NMEM) / 32 + (NH * SEQ) / 64), 256, 0, stream>>>(
        query, kmem, kinvg, qinvg);
    praxis_main<<<dim3(NH * (SEQ / TQ)), NTHR, 0, stream>>>(
        query, outputs, gate, kmem, vmem, kinvg, qinvg, out);
}

// Round 6
// 1665.311 us; speedup vs baseline: 1.3163x; 1.3163x over previous
//
#include <hip/hip_runtime.h>
#include <math.h>

#define NH 16
#define SEQ 2048
#define DIM 128
#define NMEM 4096
#define TOPK 16
#define TQ 64                  // q-rows per WG
#define KC 256                 // keys per chunk
#define NCHUNK (NMEM / KC)     // 16
#define BD 16                  // depth slice (floats)
#define NSLICE (DIM / BD)      // 8
#define RST 20                 // Qs/Ks slice row stride (words), b128-aligned
#define SCST 36                // Sc row stride (words)
#define NTHR 256

// ---- pre-pass: inverse norms only. Partial-sum splits bitwise-match R3:
// K rows: 8 threads/row; Q rows: 4 threads/row.
__global__ __launch_bounds__(256, 4)
void prenorm_kernel(const float* __restrict__ query,
                    const float* __restrict__ kmem,
                    float* __restrict__ kinvg,
                    float* __restrict__ qinvg)
{
    const int tid = threadIdx.x;
    const int bid = blockIdx.x;
    const int KB = (NH * NMEM) / 32;   // 2048 blocks for K (32 rows each)
    if (bid < KB) {
        const int row = bid * 32 + (tid >> 3);
        const int part = tid & 7;
        const float* p = kmem + (size_t)row * DIM + part * 16;
        float ss = 0.f;
#pragma unroll
        for (int j = 0; j < 4; ++j) {
            float4 v = *(const float4*)(p + j * 4);
            ss = fmaf(v.x, v.x, ss); ss = fmaf(v.y, v.y, ss);
            ss = fmaf(v.z, v.z, ss); ss = fmaf(v.w, v.w, ss);
        }
        ss += __shfl_xor(ss, 1);
        ss += __shfl_xor(ss, 2);
        ss += __shfl_xor(ss, 4);
        if (part == 0) kinvg[row] = 1.0f / fmaxf(sqrtf(ss), 1e-6f);
    } else {
        const int row = (bid - KB) * 64 + (tid >> 2);
        const int part = tid & 3;
        const float* p = query + (size_t)row * DIM + part * 32;
        float ss = 0.f;
#pragma unroll
        for (int j = 0; j < 8; ++j) {
            float4 v = *(const float4*)(p + j * 4);
            ss = fmaf(v.x, v.x, ss); ss = fmaf(v.y, v.y, ss);
            ss = fmaf(v.z, v.z, ss); ss = fmaf(v.w, v.w, ss);
        }
        ss += __shfl_xor(ss, 1);
        ss += __shfl_xor(ss, 2);
        if (part == 0) qinvg[row] = 1.0f / fmaxf(sqrtf(ss), 1e-6f);
    }
}

// ---------------- main fused kernel ----------------
__global__ __launch_bounds__(NTHR, 2)
void praxis_main(const float* __restrict__ query,
                 const float* __restrict__ outputs,
                 const float* __restrict__ gate,
                 const float* __restrict__ kmem,
                 const float* __restrict__ vmem,
                 const float* __restrict__ kinvg,
                 const float* __restrict__ qinvg,
                 float* __restrict__ out)
{
    __shared__ union SM {
        struct {
            float Qs[2][TQ * RST];     // 10 KB
            float Ks[2][KC * RST];     // 40 KB
            float Sc[2][TQ * SCST];    // 18 KB
        } a;                            // 68 KB
        struct {
            float fs[TQ][64]; int fi[TQ][64];
            float tks[TQ][TOPK]; int tki[TQ][TOPK];
        } b;                            // 40 KB
    } sm;

    const int tid = threadIdx.x;
    const int h  = blockIdx.x >> 5;        // 32 q-tiles per head
    const int q0 = (blockIdx.x & 31) * TQ;

    const float* Qg = query + ((size_t)h * SEQ + q0) * DIM;
    const float* Kg = kmem + (size_t)h * NMEM * DIM;
    const float* Vg = vmem + (size_t)h * NMEM * DIM;

    // thread roles
    const int qg = tid >> 5;   // 0..7   GEMM q-group (rows qg+8i)
    const int kg = tid & 31;   // 0..31  GEMM k-group (cols kg+32j)
    const int row = tid >> 2;  // 0..63  stage/filter/epilogue q-row
    const int part = tid & 3;  // 0..3

    const float qinv_r = qinvg[h * SEQ + q0 + row];   // for staged Q row

    // per-thread running top-16 (sorted ascending, ls[0] = threshold)
    float ls[TOPK]; int li[TOPK];
#pragma unroll
    for (int t = 0; t < TOPK; ++t) { ls[t] = -1e30f; li[t] = 0; }

    // prefetch slice t=0 (chunk 0): K key=tid 16 floats, Q row f4
    float4 kreg[4]; float4 qreg;
    {
        const float* kp = Kg + (size_t)tid * DIM;
#pragma unroll
        for (int j = 0; j < 4; ++j) kreg[j] = *(const float4*)(kp + j * 4);
        qreg = *(const float4*)(Qg + (size_t)row * DIM + part * 4);
    }
    float kinv_next = kinvg[h * NMEM + tid];   // chunk 0, key tid

#pragma unroll 1
    for (int c = 0; c < NCHUNK; ++c) {
        const float kinv_cur = kinv_next;
        if (c + 1 < NCHUNK) kinv_next = kinvg[h * NMEM + (c + 1) * KC + tid];

        float acc[8][8];
#pragma unroll
        for (int i = 0; i < 8; ++i)
#pragma unroll
            for (int j = 0; j < 8; ++j) acc[i][j] = 0.f;

#pragma unroll 1
        for (int s = 0; s < NSLICE; ++s) {
            const int buf = s & 1;
            // stage prefetched regs -> LDS, normalized (bitwise = R3's values)
            {
                float* kd = &sm.a.Ks[buf][tid * RST];
#pragma unroll
                for (int j = 0; j < 4; ++j) {
                    float4 v = kreg[j];
                    v.x *= kinv_cur; v.y *= kinv_cur; v.z *= kinv_cur; v.w *= kinv_cur;
                    *(float4*)(kd + j * 4) = v;
                }
                float4 q = qreg;
                q.x *= qinv_r; q.y *= qinv_r; q.z *= qinv_r; q.w *= qinv_r;
                *(float4*)(&sm.a.Qs[buf][row * RST + part * 4]) = q;
            }
            __syncthreads();
            // prefetch next slice
            {
                int t = c * NSLICE + s + 1;
                if (t < NCHUNK * NSLICE) {
                    int nc = t >> 3, d0 = (t & 7) * BD;
                    const float* kp = Kg + (size_t)(nc * KC + tid) * DIM + d0;
#pragma unroll
                    for (int j = 0; j < 4; ++j) kreg[j] = *(const float4*)(kp + j * 4);
                    qreg = *(const float4*)(Qg + (size_t)row * DIM + d0 + part * 4);
                }
            }
            // compute: 4 depth-quads, 8q x 8k per thread, sequential d order
#pragma unroll
            for (int d4 = 0; d4 < 4; ++d4) {
                float4 kb[8];
#pragma unroll
                for (int j = 0; j < 8; ++j)
                    kb[j] = *(const float4*)(&sm.a.Ks[buf][(kg + 32 * j) * RST + d4 * 4]);
#pragma unroll
                for (int i = 0; i < 8; ++i) {
                    float4 qa = *(const float4*)(&sm.a.Qs[buf][(qg + 8 * i) * RST + d4 * 4]);
#pragma unroll
                    for (int j = 0; j < 8; ++j) {
                        acc[i][j] = fmaf(qa.x, kb[j].x, acc[i][j]);
                        acc[i][j] = fmaf(qa.y, kb[j].y, acc[i][j]);
                        acc[i][j] = fmaf(qa.z, kb[j].z, acc[i][j]);
                        acc[i][j] = fmaf(qa.w, kb[j].w, acc[i][j]);
                    }
                }
            }
        }

        // ---- dump + filter, 8 rounds of 32 keys, double-buffered Sc halves ----
        // FULLY UNROLLED: r must be compile-time so acc[i][r] never forces
        // the accumulator array into scratch (R5's 7.4 GB write regression).
#pragma unroll
        for (int r = 0; r < 8; ++r) {
            const int half = r & 1;
            {
#pragma unroll
                for (int i = 0; i < 8; ++i)
                    sm.a.Sc[half][(qg + 8 * i) * SCST + kg] = acc[i][r];
            }
            __syncthreads();
            {
                float4 s0 = *(const float4*)(&sm.a.Sc[half][row * SCST + part * 8]);
                float4 s1 = *(const float4*)(&sm.a.Sc[half][row * SCST + part * 8 + 4]);
                int b0 = c * KC + r * 32 + part * 8;
                float mnv = ls[0];
                float4 grp[2] = { s0, s1 };
#pragma unroll
                for (int g = 0; g < 2; ++g) {
                    float4 v = grp[g];
                    int bg = b0 + g * 4;
                    float m01 = fmaxf(v.x, v.y); int i01 = (v.x >= v.y) ? 0 : 1;
                    float m23 = fmaxf(v.z, v.w); int i23 = (v.z >= v.w) ? 2 : 3;
                    float m   = fmaxf(m01, m23); int im  = (m01 >= m23) ? i01 : i23;
                    while (__ballot(m > mnv)) {
                        if (m > mnv) {
                            float s = m; int id = bg + im;
                            bool bp = true;
#pragma unroll
                            for (int t = 0; t < TOPK - 1; ++t) {
                                bool bt = s > ls[t + 1];
                                float nv = bt ? ls[t + 1] : (bp ? s : ls[t]);
                                int   ni = bt ? li[t + 1] : (bp ? id : li[t]);
                                ls[t] = nv; li[t] = ni; bp = bt;
                            }
                            ls[TOPK - 1] = bp ? s : ls[TOPK - 1];
                            li[TOPK - 1] = bp ? id : li[TOPK - 1];
                            mnv = ls[0];
                            v.x = (im == 0) ? -3e38f : v.x;
                            v.y = (im == 1) ? -3e38f : v.y;
                            v.z = (im == 2) ? -3e38f : v.z;
                            v.w = (im == 3) ? -3e38f : v.w;
                            m01 = fmaxf(v.x, v.y); i01 = (v.x >= v.y) ? 0 : 1;
                            m23 = fmaxf(v.z, v.w); i23 = (v.z >= v.w) ? 2 : 3;
                            m   = fmaxf(m01, m23); im  = (m01 >= m23) ? i01 : i23;
                        }
                    }
                }
            }
        }
    }

    __syncthreads();  // repurpose LDS as phase-b
    {
#pragma unroll
        for (int t = 0; t < TOPK; ++t) {
            sm.b.fs[row][part * TOPK + t] = ls[t];
            sm.b.fi[row][part * TOPK + t] = li[t];
        }
    }
    __syncthreads();
    // final selection: one wave per 16 rows; 16 rounds of wave-max over 64 cands
    {
        int wv = tid >> 6, lane = tid & 63;
        for (int rr = 0; rr < 16; ++rr) {
            int rw = wv * 16 + rr;
            float s = sm.b.fs[rw][lane];
            int  id = sm.b.fi[rw][lane];
#pragma unroll 1
            for (int it = 0; it < TOPK; ++it) {
                float m = s;
#pragma unroll
                for (int off = 32; off >= 1; off >>= 1)
                    m = fmaxf(m, __shfl_xor(m, off));
                unsigned long long bal = __ballot(s == m);
                int who = (int)__ffsll(bal) - 1;
                int selid = __shfl(id, who);
                if (lane == 0) { sm.b.tks[rw][it] = m; sm.b.tki[rw][it] = selid; }
                if (lane == who) s = -3e38f;
            }
        }
    }
    __syncthreads();
    // ---- epilogue: gather V, weighted sum (descending order), gate blend ----
    {
        float4 acc[8];
#pragma unroll
        for (int j = 0; j < 8; ++j) acc[j] = make_float4(0.f, 0.f, 0.f, 0.f);
#pragma unroll 1
        for (int t = 0; t < TOPK; ++t) {
            float s = sm.b.tks[row][t];
            int idx = sm.b.tki[row][t];
            const float* vp = Vg + (size_t)idx * DIM + part * 32;
#pragma unroll
            for (int j = 0; j < 8; ++j) {
                float4 v = *(const float4*)(vp + j * 4);
                acc[j].x = fmaf(s, v.x, acc[j].x);
                acc[j].y = fmaf(s, v.y, acc[j].y);
                acc[j].z = fmaf(s, v.z, acc[j].z);
                acc[j].w = fmaf(s, v.w, acc[j].w);
            }
        }
        float g = 1.0f / (1.0f + expf(-gate[h]));
        float og = 1.0f - g;
        size_t ob = ((size_t)h * SEQ + q0 + row) * DIM + part * 32;
#pragma unroll
        for (int j = 0; j < 8; ++j) {
            float4 o = *(const float4*)(outputs + ob + j * 4);
            float4 r;
            r.x = g * acc[j].x + og * o.x;
            r.y = g * acc[j].y + og * o.y;
            r.z = g * acc[j].z + og * o.z;
            r.w = g * acc[j].w + og * o.w;
            *(float4*)(out + ob + j * 4) = r;
        }
    }
}

extern "C" void kernel_launch(void* const* d_in, const int* in_sizes, int n_in,
                              void* d_out, int out_size, void* d_ws, size_t ws_size,
                              hipStream_t stream) {
    (void)in_sizes; (void)n_in; (void)out_size; (void)ws_size;
    const float* query   = (const float*)d_in[1];
    const float* outputs = (const float*)d_in[4];
    const float* gate    = (const float*)d_in[5];
    const float* kmem    = (const float*)d_in[6];
    const float* vmem    = (const float*)d_in[7];
    float* out = (float*)d_out;
    float* kinvg = (float*)d_ws;                 // 16*4096 floats
    float* qinvg = kinvg + NH * NMEM;            // 16*2048 floats (total 384 KB)

    prenorm_kernel<<<dim3((NH * NMEM) / 32 + (NH * SEQ) / 64), 256, 0, stream>>>(
        query, kmem, kinvg, qinvg);
    praxis_main<<<dim3(NH * (SEQ / TQ)), NTHR, 0, stream>>>(
        query, outputs, gate, kmem, vmem, kinvg, qinvg, out);
}